// Round 4
// baseline (601.825 us; speedup 1.0000x reference)
//
#include <hip/hip_runtime.h>
#include <hip/hip_bf16.h>

// Problem shape (fixed by setup_inputs)
#define B_DIM 512
#define L_DIM 16384
#define TPB   512                 // threads per block, kernel 1
#define KSTEPS (L_DIM / TPB)      // 32 timesteps per thread
#define GAMMA_C 2.0f
#define CONT_W  0.05f

#define LOG2E 1.4426950408889634f
#define LN2F  0.6931471805599453f
#define NEGB  -1e30f

#if __has_builtin(__builtin_amdgcn_exp2f)
#define EXP2F(x) __builtin_amdgcn_exp2f(x)
#else
#define EXP2F(x) exp2f(x)
#endif
#if __has_builtin(__builtin_amdgcn_logf)
#define LOG2F(x) __builtin_amdgcn_logf(x)   // v_log_f32 is log2
#else
#define LOG2F(x) log2f(x)
#endif

// log2-domain logsumexp of 3
__device__ __forceinline__ float lse2_3(float a, float b, float c) {
    float m = fmaxf(fmaxf(a, b), c);          // v_max3_f32
    float s = EXP2F(a - m) + EXP2F(b - m) + EXP2F(c - m);
    return m + LOG2F(s);
}

__device__ __forceinline__ float sel3(int k, float a, float b, float c) {
    return (k == 0) ? a : ((k == 1) ? b : c);
}

// -------- Kernel 1: one block per sequence --------
// Produces, per sequence b, 16 floats in ws:
//  [0..8]  P (log2-domain product of M_1..M_{L-1}, row-major)
//  [9]     score partial (log2 domain, t>=1 terms)
//  [10]    sum focal_tok*valid
//  [11]    n_valid
//  [12]    n_trans candidates (sum valid[:,1:])
//  [13]    transitions*valid count
//  [14]    mask count (for seq_end)
__global__ __launch_bounds__(TPB) void pass1(
    const float* __restrict__ logits,
    const int* __restrict__ targets,
    const int* __restrict__ mask,            // jnp.bool_ arrives as int32
    const float* __restrict__ trans,
    float* __restrict__ partials)
{
    const int b   = blockIdx.x;
    const int tid = threadIdx.x;
    const size_t base = (size_t)b * L_DIM;

    // transitions, log2-scaled, in scalar registers
    float T00 = trans[0] * LOG2E, T01 = trans[1] * LOG2E, T02 = trans[2] * LOG2E;
    float T10 = trans[3] * LOG2E, T11 = trans[4] * LOG2E, T12 = trans[5] * LOG2E;
    float T20 = trans[6] * LOG2E, T21 = trans[7] * LOG2E, T22 = trans[8] * LOG2E;

    const int t0 = tid * KSTEPS;

    // P = identity in log semiring
    float P00 = 0.f,  P01 = NEGB, P02 = NEGB;
    float P10 = NEGB, P11 = 0.f,  P12 = NEGB;
    float P20 = NEGB, P21 = NEGB, P22 = 0.f;

    // boundary state from t0-1
    int pred_prev = 0, tag_prev = 0;
    if (t0 > 0) {
        const float* r = logits + (base + t0 - 1) * 3;
        float a = r[0], bb = r[1], c = r[2];
        pred_prev = (bb > a) ? ((c > bb) ? 2 : 1) : ((c > a) ? 2 : 0);
        int tp = targets[base + t0 - 1];
        tag_prev = (tp < 0) ? 0 : ((tp > 2) ? 2 : tp);
    }

    float scoreP = 0.f, focalP = 0.f, nvalidP = 0.f;
    float ntransP = 0.f, tcountP = 0.f, mcountP = 0.f;

    #pragma unroll 1
    for (int s = 0; s < KSTEPS; ++s) {
        const int t = t0 + s;
        const float* r = logits + (base + t) * 3;
        const float e0 = r[0], e1 = r[1], e2 = r[2];
        const int   tgt = targets[base + t];
        const bool  mb  = mask[base + t] != 0;
        mcountP += mb ? 1.f : 0.f;
        const bool valid = mb && (tgt >= 0) && (tgt < 3);
        const int  tag   = (tgt < 0) ? 0 : ((tgt > 2) ? 2 : tgt);

        const float f0 = e0 * LOG2E, f1 = e1 * LOG2E, f2 = e2 * LOG2E;

        // focal
        {
            float Z  = lse2_3(f0, f1, f2);
            float ft = sel3(tag, f0, f1, f2);
            float ce2 = Z - ft;                 // log2-domain CE
            float ce  = ce2 * LN2F;
            float pt  = EXP2F(-ce2);
            float om  = 1.f - pt;
            if (valid) { focalP += om * om * ce; nvalidP += 1.f; }
        }

        // argmax (first-occurrence tie-break, strict >)
        const int pred = (e1 > e0) ? ((e2 > e1) ? 2 : 1) : ((e2 > e0) ? 2 : 0);

        if (t >= 1) {
            if (valid) { ntransP += 1.f; if (pred != pred_prev) tcountP += 1.f; }
            if (mb) {
                // path score term
                float c0 = sel3(tag, T00, T01, T02);
                float c1 = sel3(tag, T10, T11, T12);
                float c2 = sel3(tag, T20, T21, T22);
                scoreP += sel3(tag_prev, c0, c1, c2) + sel3(tag, f0, f1, f2);
                // absorb M_t: newP[i][j] = lse(P[i][k] + T[k][j]) + f[j]
                float n00 = lse2_3(P00 + T00, P01 + T10, P02 + T20) + f0;
                float n01 = lse2_3(P00 + T01, P01 + T11, P02 + T21) + f1;
                float n02 = lse2_3(P00 + T02, P01 + T12, P02 + T22) + f2;
                float n10 = lse2_3(P10 + T00, P11 + T10, P12 + T20) + f0;
                float n11 = lse2_3(P10 + T01, P11 + T11, P12 + T21) + f1;
                float n12 = lse2_3(P10 + T02, P11 + T12, P12 + T22) + f2;
                float n20 = lse2_3(P20 + T00, P21 + T10, P22 + T20) + f0;
                float n21 = lse2_3(P20 + T01, P21 + T11, P22 + T21) + f1;
                float n22 = lse2_3(P20 + T02, P21 + T12, P22 + T22) + f2;
                P00 = n00; P01 = n01; P02 = n02;
                P10 = n10; P11 = n11; P12 = n12;
                P20 = n20; P21 = n21; P22 = n22;
            }
        }
        pred_prev = pred; tag_prev = tag;
    }

    // ---- block tree-reduction ----
    __shared__ float sP[TPB][9];
    __shared__ float sS[TPB][6];
    sP[tid][0] = P00; sP[tid][1] = P01; sP[tid][2] = P02;
    sP[tid][3] = P10; sP[tid][4] = P11; sP[tid][5] = P12;
    sP[tid][6] = P20; sP[tid][7] = P21; sP[tid][8] = P22;
    sS[tid][0] = scoreP; sS[tid][1] = focalP; sS[tid][2] = nvalidP;
    sS[tid][3] = ntransP; sS[tid][4] = tcountP; sS[tid][5] = mcountP;
    __syncthreads();

    for (int off = 1; off < TPB; off <<= 1) {
        if ((tid & (2 * off - 1)) == 0) {
            float A[9], Bm[9], Cn[9];
            #pragma unroll
            for (int k = 0; k < 9; ++k) { A[k] = sP[tid][k]; Bm[k] = sP[tid + off][k]; }
            #pragma unroll
            for (int i = 0; i < 3; ++i)
                #pragma unroll
                for (int j = 0; j < 3; ++j)
                    Cn[i * 3 + j] = lse2_3(A[i * 3 + 0] + Bm[0 * 3 + j],
                                           A[i * 3 + 1] + Bm[1 * 3 + j],
                                           A[i * 3 + 2] + Bm[2 * 3 + j]);
            #pragma unroll
            for (int k = 0; k < 9; ++k) sP[tid][k] = Cn[k];
            #pragma unroll
            for (int k = 0; k < 6; ++k) sS[tid][k] += sS[tid + off][k];
        }
        __syncthreads();
    }

    if (tid == 0) {
        float* o = partials + (size_t)b * 16;
        #pragma unroll
        for (int k = 0; k < 9; ++k) o[k] = sP[0][k];
        #pragma unroll
        for (int k = 0; k < 6; ++k) o[9 + k] = sS[0][k];
        o[15] = 0.f;
    }
}

// -------- Kernel 2: finalize, one thread per sequence, single block --------
__global__ __launch_bounds__(B_DIM) void pass2(
    const float* __restrict__ logits,
    const int* __restrict__ targets,
    const float* __restrict__ start_trans,
    const float* __restrict__ end_trans,
    const float* __restrict__ partials,
    float* __restrict__ out)
{
    const int tid = threadIdx.x;
    double v_llh = 0.0, v_focal = 0.0, v_nv = 0.0, v_nt = 0.0, v_tc = 0.0;

    {
        const int b = tid;
        const float* pp = partials + (size_t)b * 16;
        float P[9];
        #pragma unroll
        for (int k = 0; k < 9; ++k) P[k] = pp[k];
        const float score2 = pp[9];
        v_focal = (double)pp[10];
        v_nv    = (double)pp[11];
        v_nt    = (double)pp[12];
        v_tc    = (double)pp[13];
        const float mcount = pp[14];

        const size_t base = (size_t)b * L_DIM;
        const float e0 = logits[base * 3 + 0];
        const float e1 = logits[base * 3 + 1];
        const float e2 = logits[base * 3 + 2];
        const int tg0  = targets[base];
        const int tag0 = (tg0 < 0) ? 0 : ((tg0 > 2) ? 2 : tg0);

        const float a0 = (start_trans[0] + e0) * LOG2E;
        const float a1 = (start_trans[1] + e1) * LOG2E;
        const float a2 = (start_trans[2] + e2) * LOG2E;
        // alpha_final = alpha0 (x) P
        const float af0 = lse2_3(a0 + P[0], a1 + P[3], a2 + P[6]);
        const float af1 = lse2_3(a0 + P[1], a1 + P[4], a2 + P[7]);
        const float af2 = lse2_3(a0 + P[2], a1 + P[5], a2 + P[8]);
        const float den2 = lse2_3(af0 + end_trans[0] * LOG2E,
                                  af1 + end_trans[1] * LOG2E,
                                  af2 + end_trans[2] * LOG2E);
        const float den = den2 * LN2F;

        int seq_end = (int)(mcount + 0.5f) - 1;
        if (seq_end < 0) seq_end = 0;
        const int ltg = targets[base + seq_end];
        const int last_tag = (ltg < 0) ? 0 : ((ltg > 2) ? 2 : ltg);

        const float sc0 = start_trans[tag0] + sel3(tag0, e0, e1, e2);
        const float numer = sc0 + score2 * LN2F + end_trans[last_tag];
        v_llh = (double)numer - (double)den;
    }

    __shared__ double sred[B_DIM];
    double tot[5];
    double vals[5] = { v_llh, v_focal, v_nv, v_nt, v_tc };
    for (int q = 0; q < 5; ++q) {
        sred[tid] = vals[q];
        __syncthreads();
        for (int off = B_DIM / 2; off > 0; off >>= 1) {
            if (tid < off) sred[tid] += sred[tid + off];
            __syncthreads();
        }
        if (tid == 0) tot[q] = sred[0];
        __syncthreads();
    }

    if (tid == 0) {
        double nvv = (tot[2] > 1.0) ? tot[2] : 1.0;
        double ntt = (tot[3] > 1.0) ? tot[3] : 1.0;
        double focal_mean = tot[1] / nvv;
        double crf = -(tot[0] / (double)B_DIM);
        double cont = tot[4] / ntt;
        out[0] = (float)(focal_mean + crf + (double)CONT_W * cont);
    }
}

extern "C" void kernel_launch(void* const* d_in, const int* in_sizes, int n_in,
                              void* d_out, int out_size, void* d_ws, size_t ws_size,
                              hipStream_t stream) {
    const float* logits       = (const float*)d_in[0];
    const int*   targets      = (const int*)d_in[1];
    const int*   mask         = (const int*)d_in[2];   // bool stored as int32
    const float* start_trans  = (const float*)d_in[3];
    const float* end_trans    = (const float*)d_in[4];
    const float* trans        = (const float*)d_in[5];
    float* out = (float*)d_out;
    float* partials = (float*)d_ws;   // 512 * 16 floats = 32 KB

    pass1<<<B_DIM, TPB, 0, stream>>>(logits, targets, mask, trans, partials);
    pass2<<<1, B_DIM, 0, stream>>>(logits, targets, start_trans, end_trans, partials, out);
}

// Round 5
// 251.460 us; speedup vs baseline: 2.3933x; 2.3933x over previous
//
#include <hip/hip_runtime.h>
#include <hip/hip_bf16.h>

// Problem shape (fixed by setup_inputs)
#define B_DIM 512
#define L_DIM 16384
#define TPB   512                 // threads per block, kernel 1
#define KSTEPS 32                 // timesteps per thread
#define NGROUP 4                  // 4 groups of 8 steps
#define CONT_W  0.05f

#define LOG2E 1.4426950408889634f
#define LN2F  0.6931471805599453f

#if __has_builtin(__builtin_amdgcn_exp2f)
#define EXP2F(x) __builtin_amdgcn_exp2f(x)
#else
#define EXP2F(x) exp2f(x)
#endif
#if __has_builtin(__builtin_amdgcn_logf)
#define LOG2F(x) __builtin_amdgcn_logf(x)   // v_log_f32 is log2
#else
#define LOG2F(x) log2f(x)
#endif
#if __has_builtin(__builtin_amdgcn_rcpf)
#define RCPF(x) __builtin_amdgcn_rcpf(x)
#else
#define RCPF(x) (1.0f / (x))
#endif

__device__ __forceinline__ float lse2_3(float a, float b, float c) {
    float m = fmaxf(fmaxf(a, b), c);
    float s = EXP2F(a - m) + EXP2F(b - m) + EXP2F(c - m);
    return m + LOG2F(s);
}

__device__ __forceinline__ float sel3(int k, float a, float b, float c) {
    return (k == 0) ? a : ((k == 1) ? b : c);
}

// -------- Kernel 1: one block per sequence --------
// Per sequence b, 16 floats in ws:
//  [0..8] P (LINEAR domain, row-major, scaled)  [9] s (log2 scale)
//  [10] score partial (log2 domain, t>=1)  [11] focal sum  [12] n_valid
//  [13] n_trans candidates  [14] transition count  [15] mask count
__global__ __launch_bounds__(TPB) void pass1(
    const float* __restrict__ logits,
    const int* __restrict__ targets,
    const int* __restrict__ mask,            // jnp.bool_ arrives as int32
    const float* __restrict__ trans,
    float* __restrict__ partials)
{
    const int b   = blockIdx.x;
    const int tid = threadIdx.x;
    const size_t base = (size_t)b * L_DIM;

    // transitions in log2 domain + their linear forms W = 2^T
    const float t00 = trans[0]*LOG2E, t01 = trans[1]*LOG2E, t02 = trans[2]*LOG2E;
    const float t10 = trans[3]*LOG2E, t11 = trans[4]*LOG2E, t12 = trans[5]*LOG2E;
    const float t20 = trans[6]*LOG2E, t21 = trans[7]*LOG2E, t22 = trans[8]*LOG2E;
    const float w00 = EXP2F(t00), w01 = EXP2F(t01), w02 = EXP2F(t02);
    const float w10 = EXP2F(t10), w11 = EXP2F(t11), w12 = EXP2F(t12);
    const float w20 = EXP2F(t20), w21 = EXP2F(t21), w22 = EXP2F(t22);

    const int t0 = tid * KSTEPS;

    // P = identity (linear), scale s_acc (log2)
    float p00 = 1.f, p01 = 0.f, p02 = 0.f;
    float p10 = 0.f, p11 = 1.f, p12 = 0.f;
    float p20 = 0.f, p21 = 0.f, p22 = 1.f;
    float s_acc = 0.f;

    // boundary state from t0-1
    int pred_prev = 0, tag_prev = 0;
    if (t0 > 0) {
        const float* r = logits + (base + t0 - 1) * 3;
        float a = r[0], bb = r[1], c = r[2];
        pred_prev = (bb > a) ? ((c > bb) ? 2 : 1) : ((c > a) ? 2 : 0);
        int tp = targets[base + t0 - 1];
        tag_prev = (tp < 0) ? 0 : ((tp > 2) ? 2 : tp);
    }

    float score2 = 0.f, focalP = 0.f, nvalidP = 0.f;
    float ntransP = 0.f, tcountP = 0.f, mcountP = 0.f;

    auto doStep = [&](int t, float e0, float e1, float e2, int tgt, int mkv) {
        const bool mb = (mkv != 0);
        mcountP += mb ? 1.f : 0.f;
        const bool valid = mb && (tgt >= 0) && (tgt < 3);
        const int  tag   = (tgt < 0) ? 0 : ((tgt > 2) ? 2 : tgt);
        const float f0 = e0 * LOG2E, f1 = e1 * LOG2E, f2 = e2 * LOG2E;
        // linear emission factors, shared by focal + absorb
        const float E0 = EXP2F(f0), E1 = EXP2F(f1), E2 = EXP2F(f2);
        const float S  = E0 + E1 + E2;
        const float ftag = sel3(tag, f0, f1, f2);
        // focal: pt = softmax_tag, ce = ln S/E_tag
        const float ce2 = LOG2F(S) - ftag;
        const float pt  = sel3(tag, E0, E1, E2) * RCPF(S);
        const float om  = 1.f - pt;
        if (valid) { focalP += om * om * (ce2 * LN2F); nvalidP += 1.f; }
        const int pred = (e1 > e0) ? ((e2 > e1) ? 2 : 1) : ((e2 > e0) ? 2 : 0);
        if (t >= 1) {
            if (valid) { ntransP += 1.f; tcountP += (pred != pred_prev) ? 1.f : 0.f; }
            if (mb) {
                // path score (log2 domain)
                const float c0 = sel3(tag, t00, t01, t02);
                const float c1 = sel3(tag, t10, t11, t12);
                const float c2 = sel3(tag, t20, t21, t22);
                score2 += sel3(tag_prev, c0, c1, c2) + ftag;
                // absorb linearly: P <- P * (W .* colE)
                const float a00 = w00*E0, a01 = w01*E1, a02 = w02*E2;
                const float a10 = w10*E0, a11 = w11*E1, a12 = w12*E2;
                const float a20 = w20*E0, a21 = w21*E1, a22 = w22*E2;
                const float n00 = p00*a00 + p01*a10 + p02*a20;
                const float n01 = p00*a01 + p01*a11 + p02*a21;
                const float n02 = p00*a02 + p01*a12 + p02*a22;
                const float n10 = p10*a00 + p11*a10 + p12*a20;
                const float n11 = p10*a01 + p11*a11 + p12*a21;
                const float n12 = p10*a02 + p11*a12 + p12*a22;
                const float n20 = p20*a00 + p21*a10 + p22*a20;
                const float n21 = p20*a01 + p21*a11 + p22*a21;
                const float n22 = p20*a02 + p21*a12 + p22*a22;
                p00 = n00; p01 = n01; p02 = n02;
                p10 = n10; p11 = n11; p12 = n12;
                p20 = n20; p21 = n21; p22 = n22;
            }
        }
        pred_prev = pred; tag_prev = tag;
    };

    // wide-staged main loop: per group, 6x float4 logits + 2x int4 targets + 2x int4 mask
    const float4* Lp = reinterpret_cast<const float4*>(logits + (base + (size_t)t0) * 3);
    const int4*   Tp = reinterpret_cast<const int4*>(targets + base + t0);
    const int4*   Mp = reinterpret_cast<const int4*>(mask    + base + t0);

    #pragma unroll 1
    for (int g = 0; g < NGROUP; ++g) {
        float la[24]; int ta[8]; int ma[8];
        #pragma unroll
        for (int j = 0; j < 6; ++j)
            *reinterpret_cast<float4*>(&la[4 * j]) = Lp[g * 6 + j];
        *reinterpret_cast<int4*>(&ta[0]) = Tp[g * 2 + 0];
        *reinterpret_cast<int4*>(&ta[4]) = Tp[g * 2 + 1];
        *reinterpret_cast<int4*>(&ma[0]) = Mp[g * 2 + 0];
        *reinterpret_cast<int4*>(&ma[4]) = Mp[g * 2 + 1];

        const int tg = t0 + g * 8;
        #pragma unroll
        for (int u = 0; u < 8; ++u)
            doStep(tg + u, la[u * 3 + 0], la[u * 3 + 1], la[u * 3 + 2], ta[u], ma[u]);

        // rescale by exponent of max entry (no transcendentals)
        float mx = fmaxf(fmaxf(fmaxf(fmaxf(p00, p01), fmaxf(p02, p10)),
                               fmaxf(fmaxf(p11, p12), fmaxf(p20, p21))), p22);
        const unsigned bbits = __float_as_uint(mx);
        const int ex = (int)((bbits >> 23) & 255u) - 127;
        const float sc = __uint_as_float((unsigned)(127 - ex) << 23);  // 2^-ex
        p00 *= sc; p01 *= sc; p02 *= sc;
        p10 *= sc; p11 *= sc; p12 *= sc;
        p20 *= sc; p21 *= sc; p22 *= sc;
        s_acc += (float)ex;
    }

    // ---- block tree-reduction (linear matrices + scales) ----
    __shared__ float sP[TPB][10];
    __shared__ float sS[TPB][6];
    sP[tid][0] = p00; sP[tid][1] = p01; sP[tid][2] = p02;
    sP[tid][3] = p10; sP[tid][4] = p11; sP[tid][5] = p12;
    sP[tid][6] = p20; sP[tid][7] = p21; sP[tid][8] = p22;
    sP[tid][9] = s_acc;
    sS[tid][0] = score2; sS[tid][1] = focalP; sS[tid][2] = nvalidP;
    sS[tid][3] = ntransP; sS[tid][4] = tcountP; sS[tid][5] = mcountP;
    __syncthreads();

    for (int off = 1; off < TPB; off <<= 1) {
        if ((tid & (2 * off - 1)) == 0) {
            float A[9], Bm[9], Cn[9];
            #pragma unroll
            for (int k = 0; k < 9; ++k) { A[k] = sP[tid][k]; Bm[k] = sP[tid + off][k]; }
            float s = sP[tid][9] + sP[tid + off][9];
            #pragma unroll
            for (int i = 0; i < 3; ++i)
                #pragma unroll
                for (int j = 0; j < 3; ++j)
                    Cn[i * 3 + j] = A[i * 3 + 0] * Bm[0 * 3 + j]
                                  + A[i * 3 + 1] * Bm[1 * 3 + j]
                                  + A[i * 3 + 2] * Bm[2 * 3 + j];
            float mx = Cn[0];
            #pragma unroll
            for (int k = 1; k < 9; ++k) mx = fmaxf(mx, Cn[k]);
            const unsigned bbits = __float_as_uint(mx);
            const int ex = (int)((bbits >> 23) & 255u) - 127;
            const float sc = __uint_as_float((unsigned)(127 - ex) << 23);
            #pragma unroll
            for (int k = 0; k < 9; ++k) sP[tid][k] = Cn[k] * sc;
            sP[tid][9] = s + (float)ex;
            #pragma unroll
            for (int k = 0; k < 6; ++k) sS[tid][k] += sS[tid + off][k];
        }
        __syncthreads();
    }

    if (tid == 0) {
        float* o = partials + (size_t)b * 16;
        #pragma unroll
        for (int k = 0; k < 10; ++k) o[k] = sP[0][k];
        #pragma unroll
        for (int k = 0; k < 6; ++k) o[10 + k] = sS[0][k];
    }
}

// -------- Kernel 2: finalize, one thread per sequence, single block --------
__global__ __launch_bounds__(B_DIM) void pass2(
    const float* __restrict__ logits,
    const int* __restrict__ targets,
    const float* __restrict__ start_trans,
    const float* __restrict__ end_trans,
    const float* __restrict__ partials,
    float* __restrict__ out)
{
    const int tid = threadIdx.x;
    double v_llh, v_focal, v_nv, v_nt, v_tc;

    {
        const int b = tid;
        const float* pp = partials + (size_t)b * 16;
        float P[9];
        #pragma unroll
        for (int k = 0; k < 9; ++k) P[k] = pp[k];
        const float s_scale = pp[9];
        const float score2  = pp[10];
        v_focal = (double)pp[11];
        v_nv    = (double)pp[12];
        v_nt    = (double)pp[13];
        v_tc    = (double)pp[14];
        const float mcount = pp[15];

        const size_t base = (size_t)b * L_DIM;
        const float e0 = logits[base * 3 + 0];
        const float e1 = logits[base * 3 + 1];
        const float e2 = logits[base * 3 + 2];
        const int tg0  = targets[base];
        const int tag0 = (tg0 < 0) ? 0 : ((tg0 > 2) ? 2 : tg0);

        // alpha0 (log2) -> linear with shared shift am
        const float a0 = (start_trans[0] + e0) * LOG2E;
        const float a1 = (start_trans[1] + e1) * LOG2E;
        const float a2 = (start_trans[2] + e2) * LOG2E;
        const float am = fmaxf(fmaxf(a0, a1), a2);
        const float al0 = EXP2F(a0 - am), al1 = EXP2F(a1 - am), al2 = EXP2F(a2 - am);
        // alpha_final = alpha0(row) x P (linear)
        const float af0 = al0 * P[0] + al1 * P[3] + al2 * P[6];
        const float af1 = al0 * P[1] + al1 * P[4] + al2 * P[7];
        const float af2 = al0 * P[2] + al1 * P[5] + al2 * P[8];
        const float et0 = EXP2F(end_trans[0] * LOG2E);
        const float et1 = EXP2F(end_trans[1] * LOG2E);
        const float et2 = EXP2F(end_trans[2] * LOG2E);
        const float d   = af0 * et0 + af1 * et1 + af2 * et2;
        const float den = (LOG2F(d) + am + s_scale) * LN2F;

        int seq_end = (int)(mcount + 0.5f) - 1;
        if (seq_end < 0) seq_end = 0;
        const int ltg = targets[base + seq_end];
        const int last_tag = (ltg < 0) ? 0 : ((ltg > 2) ? 2 : ltg);

        const float sc0 = start_trans[tag0] + sel3(tag0, e0, e1, e2);
        const float numer = sc0 + score2 * LN2F + end_trans[last_tag];
        v_llh = (double)numer - (double)den;
    }

    __shared__ double sred[B_DIM];
    double tot[5];
    double vals[5] = { v_llh, v_focal, v_nv, v_nt, v_tc };
    for (int q = 0; q < 5; ++q) {
        sred[tid] = vals[q];
        __syncthreads();
        for (int off = B_DIM / 2; off > 0; off >>= 1) {
            if (tid < off) sred[tid] += sred[tid + off];
            __syncthreads();
        }
        if (tid == 0) tot[q] = sred[0];
        __syncthreads();
    }

    if (tid == 0) {
        double nvv = (tot[2] > 1.0) ? tot[2] : 1.0;
        double ntt = (tot[3] > 1.0) ? tot[3] : 1.0;
        double focal_mean = tot[1] / nvv;
        double crf = -(tot[0] / (double)B_DIM);
        double cont = tot[4] / ntt;
        out[0] = (float)(focal_mean + crf + (double)CONT_W * cont);
    }
}

extern "C" void kernel_launch(void* const* d_in, const int* in_sizes, int n_in,
                              void* d_out, int out_size, void* d_ws, size_t ws_size,
                              hipStream_t stream) {
    const float* logits       = (const float*)d_in[0];
    const int*   targets      = (const int*)d_in[1];
    const int*   mask         = (const int*)d_in[2];   // bool stored as int32
    const float* start_trans  = (const float*)d_in[3];
    const float* end_trans    = (const float*)d_in[4];
    const float* trans        = (const float*)d_in[5];
    float* out = (float*)d_out;
    float* partials = (float*)d_ws;   // 512 * 16 floats = 32 KB

    pass1<<<B_DIM, TPB, 0, stream>>>(logits, targets, mask, trans, partials);
    pass2<<<1, B_DIM, 0, stream>>>(logits, targets, start_trans, end_trans, partials, out);
}